// Round 9
// baseline (88.727 us; speedup 1.0000x reference)
//
#include <hip/hip_runtime.h>
#include <hip/hip_bf16.h>

typedef __attribute__((ext_vector_type(8))) short short8;
typedef __attribute__((ext_vector_type(4))) float f32x4;
typedef __attribute__((ext_vector_type(4))) unsigned short u16x4;
typedef unsigned short u16;

#define Bn 8
#define Tn 2048
#define Cn 1024
#define Hn 64
#define Mrows (Bn * Tn)  // 16384
#define UPB 80           // split-K units per batch (q-tile 64, k-chunk 512)
#define SLOTF 4224       // floats per partial slot: 64*64 o + 64 m + 64 l

__device__ __forceinline__ u16 bfu(float f) {
    __hip_bfloat16 h = __float2bfloat16(f);
    union { __hip_bfloat16 h; u16 u; } c; c.h = h; return c.u;
}

// All three W [1024][64] f32 -> wt [3][64][1024] bf16 (transposed), scale folded.
__global__ void convert_w3(const float* __restrict__ Wq, const float* __restrict__ Wk,
                           const float* __restrict__ Wv, u16* __restrict__ wt, float qscale) {
    int widx = blockIdx.x * 256 + threadIdx.x;          // 0 .. 3*65536-1
    int mat = widx >> 16;
    int rem = widx & 65535;
    int k = rem >> 6, n = rem & 63;
    const float* W = mat == 0 ? Wq : (mat == 1 ? Wk : Wv);
    float s = mat == 0 ? qscale : 1.0f;
    wt[(size_t)mat * 65536 + n * Cn + k] = bfu(W[rem] * s);
}

// x [16384][1024] f32 @ wt^T -> q,k bf16 [16384][64] + vt bf16 [8][64][2048].
// All global loads wave-contiguous; B staged once per block (shared by 4 waves).
__global__ __launch_bounds__(256, 4) void qkv_proj(const float* __restrict__ x,
                                                   const u16* __restrict__ wt,
                                                   u16* __restrict__ qk,
                                                   u16* __restrict__ vt) {
    __shared__ u16 As[16][72];   // bf16, pad->+8: <=2-way bank conflicts
    __shared__ u16 Bs[192][72];
    const int tid = threadIdx.x;
    const int lane = tid & 63;
    const int wn = tid >> 6;          // 0..3 -> 48-col slice
    const int l15 = lane & 15;
    const int lhi = lane >> 4;
    const int row0 = blockIdx.x * 16;

    const int arow = tid >> 4;        // 0..15
    const int ac4 = (tid & 15) * 4;   // f32 col 0..60
    const float* asrc = x + (size_t)(row0 + arow) * Cn + ac4;

    f32x4 acc[3];
    for (int nj = 0; nj < 3; ++nj) acc[nj] = f32x4{0.f, 0.f, 0.f, 0.f};

    for (int ko = 0; ko < Cn; ko += 64) {
        __syncthreads();
        f32x4 av = *(const f32x4*)(asrc + ko);
        u16x4 ab;
        ab[0] = bfu(av[0]); ab[1] = bfu(av[1]);
        ab[2] = bfu(av[2]); ab[3] = bfu(av[3]);
        *(u16x4*)&As[arow][ac4] = ab;
        #pragma unroll
        for (int i = 0; i < 6; ++i) {
            int chunk = tid + 256 * i;            // 0..1535
            int brow = chunk >> 3;                // 0..191
            int bc8 = (chunk & 7) * 8;            // 0..56
            short8 bv = *(const short8*)(wt + (size_t)brow * Cn + ko + bc8);
            *(short8*)&Bs[brow][bc8] = bv;
        }
        __syncthreads();
        #pragma unroll
        for (int kc = 0; kc < 2; ++kc) {
            short8 af = *(const short8*)&As[l15][kc * 32 + lhi * 8];
            short8 bf0 = *(const short8*)&Bs[wn * 48 + l15][kc * 32 + lhi * 8];
            short8 bf1 = *(const short8*)&Bs[wn * 48 + 16 + l15][kc * 32 + lhi * 8];
            short8 bf2 = *(const short8*)&Bs[wn * 48 + 32 + l15][kc * 32 + lhi * 8];
            acc[0] = __builtin_amdgcn_mfma_f32_16x16x32_bf16(af, bf0, acc[0], 0, 0, 0);
            acc[1] = __builtin_amdgcn_mfma_f32_16x16x32_bf16(af, bf1, acc[1], 0, 0, 0);
            acc[2] = __builtin_amdgcn_mfma_f32_16x16x32_bf16(af, bf2, acc[2], 0, 0, 0);
        }
    }

    const int growb = row0 + lhi * 4;
    for (int nj = 0; nj < 3; ++nj) {
        int gcolb = wn * 48 + nj * 16 + l15;
        int mat = gcolb >> 6, lcol = gcolb & 63;
        if (mat < 2) {
            u16* dst = qk + (size_t)mat * (Mrows * Hn);
            for (int r = 0; r < 4; ++r)
                dst[(size_t)(growb + r) * Hn + lcol] = bfu(acc[nj][r]);
        } else {
            int b = growb >> 11, t = growb & 2047;
            u16x4 pk;
            pk[0] = bfu(acc[nj][0]); pk[1] = bfu(acc[nj][1]);
            pk[2] = bfu(acc[nj][2]); pk[3] = bfu(acc[nj][3]);
            *(u16x4*)(vt + ((size_t)b * Hn + lcol) * Tn + t) = pk;
        }
    }
}

// Flash attention, causal, split-K. Block = 4 waves, q-tile 64 (16 rows/wave),
// k-chunk <= 8 k-tiles of 64 keys. K/V staged in LDS once per block, shared by
// 4 waves. NOTE (round-8 postmortem): tile is 8KB = 32B/thread -> each thread
// stages TWO short8 per tile (a short8 is 8 elements, not 16).
__global__ __launch_bounds__(256) void attn_fwd(const u16* __restrict__ q,
                                                const u16* __restrict__ k,
                                                const u16* __restrict__ vt,
                                                float* __restrict__ partial) {
    __shared__ u16 Ks[64][72];
    __shared__ u16 Vs[64][72];
    __shared__ u16 pl[4][16][72];
    const int tid = threadIdx.x;
    const int lane = tid & 63;
    const int wid = tid >> 6;
    const int l15 = lane & 15, lhi = lane >> 4;
    const int bid = blockIdx.x;
    const int b = bid / UPB;
    const int u = bid - b * UPB;
    int qt, c;
    if (u < 8)        { qt = u;                   c = 0; }
    else if (u < 24)  { qt = 8 + ((u - 8) >> 1);  c = (u - 8) & 1; }
    else if (u < 48)  { qt = 16 + (u - 24) / 3;   c = (u - 24) % 3; }
    else              { qt = 24 + ((u - 48) >> 2); c = (u - 48) & 3; }
    const int nkt = qt + 1;
    const int kb0 = c * 8;
    const int kbe = min(kb0 + 8, nkt);
    const int q0w = qt * 64 + wid * 16;

    const u16* qb = q + (size_t)b * Tn * Hn;
    const u16* kbp = k + (size_t)b * Tn * Hn;
    const u16* vtb = vt + (size_t)b * Hn * Tn;

    const int srow = tid >> 2;          // 0..63
    const int scol = (tid & 3) * 16;    // 0,16,32,48 (each thread: 2 x short8)

    short8 qf[2];
    for (int kc = 0; kc < 2; ++kc)
        qf[kc] = *(const short8*)(qb + (size_t)(q0w + l15) * Hn + kc * 32 + lhi * 8);

    float m = -1e30f, lpart = 0.f;   // per-lane: q-row = l15 (4 copies across lhi)
    f32x4 o[4];
    for (int dt = 0; dt < 4; ++dt) o[dt] = f32x4{0.f, 0.f, 0.f, 0.f};

    for (int kbi = kb0; kbi < kbe; ++kbi) {
        const int k0 = kbi * 64;
        __syncthreads();
        const u16* ksrc = kbp + (size_t)(k0 + srow) * Hn + scol;
        const u16* vsrc = vtb + (size_t)srow * Tn + k0 + scol;
        *(short8*)&Ks[srow][scol]     = *(const short8*)(ksrc);
        *(short8*)&Ks[srow][scol + 8] = *(const short8*)(ksrc + 8);
        *(short8*)&Vs[srow][scol]     = *(const short8*)(vsrc);
        *(short8*)&Vs[srow][scol + 8] = *(const short8*)(vsrc + 8);
        __syncthreads();
        if (k0 > q0w + 15) continue;   // fully-masked for this wave (uniform)

        f32x4 sacc[4];
        for (int kt = 0; kt < 4; ++kt) sacc[kt] = f32x4{0.f, 0.f, 0.f, 0.f};
        #pragma unroll
        for (int kc = 0; kc < 2; ++kc) {
            #pragma unroll
            for (int kt = 0; kt < 4; ++kt) {
                short8 kf = *(const short8*)&Ks[kt * 16 + l15][kc * 32 + lhi * 8];
                sacc[kt] = __builtin_amdgcn_mfma_f32_16x16x32_bf16(kf, qf[kc], sacc[kt], 0, 0, 0);
            }
        }
        if (k0 + 63 > q0w) {  // diagonal: causal mask (per-lane, no shuffle)
            for (int kt = 0; kt < 4; ++kt)
                for (int r = 0; r < 4; ++r) {
                    int kg = k0 + kt * 16 + lhi * 4 + r;
                    if (kg > q0w + l15) sacc[kt][r] = -3.0e38f;
                }
        }
        f32x4 mx0, mx1;
        for (int e = 0; e < 4; ++e) {
            mx0[e] = fmaxf(sacc[0][e], sacc[1][e]);
            mx1[e] = fmaxf(sacc[2][e], sacc[3][e]);
        }
        float tmax = -3.0e38f;
        for (int e = 0; e < 4; ++e) tmax = fmaxf(tmax, fmaxf(mx0[e], mx1[e]));
        tmax = fmaxf(tmax, __shfl_xor(tmax, 16));
        tmax = fmaxf(tmax, __shfl_xor(tmax, 32));
        if (!__all(tmax <= m + 8.0f)) {   // defer-max (THR=8, log2 domain)
            float mnew = fmaxf(m, tmax);
            float corr = exp2f(m - mnew);
            m = mnew;
            lpart *= corr;
            for (int r = 0; r < 4; ++r) {
                float cr = __shfl(corr, lhi * 4 + r);
                for (int dt = 0; dt < 4; ++dt) o[dt][r] *= cr;
            }
        }
        float psum = 0.f;
        for (int kt = 0; kt < 4; ++kt)
            for (int r = 0; r < 4; ++r) {
                float p = exp2f(sacc[kt][r] - m);
                sacc[kt][r] = p;
                psum += p;
            }
        lpart += psum;
        for (int kt = 0; kt < 4; ++kt) {
            u16x4 pk;
            pk[0] = bfu(sacc[kt][0]); pk[1] = bfu(sacc[kt][1]);
            pk[2] = bfu(sacc[kt][2]); pk[3] = bfu(sacc[kt][3]);
            *(u16x4*)&pl[wid][l15][kt * 16 + lhi * 4] = pk;
        }
        short8 pf[2];
        for (int kc = 0; kc < 2; ++kc)
            pf[kc] = *(const short8*)&pl[wid][l15][kc * 32 + lhi * 8];
        #pragma unroll
        for (int dt = 0; dt < 4; ++dt) {
            #pragma unroll
            for (int kc = 0; kc < 2; ++kc) {
                short8 vf = *(const short8*)&Vs[dt * 16 + l15][kc * 32 + lhi * 8];
                o[dt] = __builtin_amdgcn_mfma_f32_16x16x32_bf16(pf[kc], vf, o[dt], 0, 0, 0);
            }
        }
    }
    float lsum = lpart;
    lsum += __shfl_xor(lsum, 16);
    lsum += __shfl_xor(lsum, 32);

    float* ps = partial + (size_t)bid * SLOTF;
    for (int dt = 0; dt < 4; ++dt)
        for (int r = 0; r < 4; ++r)
            ps[(wid * 16 + lhi * 4 + r) * 64 + dt * 16 + l15] = o[dt][r];
    if (lhi == 0) {
        ps[4096 + wid * 16 + l15] = m;
        ps[4160 + wid * 16 + l15] = lsum;
    }
}

// Combine <=4 split-K partials per (b, 64-row q-tile).
__global__ __launch_bounds__(256) void attn_reduce(const float* __restrict__ partial,
                                                   float* __restrict__ out) {
    const int bid = blockIdx.x;           // 0..255
    const int b = bid >> 5, qt = bid & 31;
    const int nc = qt / 8 + 1;            // = ceil((qt+1)/8)
    const int base = b * UPB +
        (qt < 8 ? qt : qt < 16 ? 8 + 2 * (qt - 8)
                     : qt < 24 ? 24 + 3 * (qt - 16) : 48 + 4 * (qt - 24));
    const int d = threadIdx.x & 63;
    const int qr = threadIdx.x >> 6;
    for (int i = 0; i < 16; ++i) {
        const int qq = i * 4 + qr;
        float M = -3.0e38f;
        #pragma unroll
        for (int cc = 0; cc < 4; ++cc)
            if (cc < nc) M = fmaxf(M, partial[(size_t)(base + cc) * SLOTF + 4096 + qq]);
        float L = 0.f, acc = 0.f;
        #pragma unroll
        for (int cc = 0; cc < 4; ++cc)
            if (cc < nc) {
                const float* ps = partial + (size_t)(base + cc) * SLOTF;
                float w = exp2f(ps[4096 + qq] - M);
                L += ps[4160 + qq] * w;
                acc += ps[qq * 64 + d] * w;
            }
        out[((size_t)b * Tn + qt * 64 + qq) * Hn + d] = acc / L;
    }
}

extern "C" void kernel_launch(void* const* d_in, const int* in_sizes, int n_in,
                              void* d_out, int out_size, void* d_ws, size_t ws_size,
                              hipStream_t stream) {
    const float* x = (const float*)d_in[0];
    const float* Wq = (const float*)d_in[1];
    const float* Wk = (const float*)d_in[2];
    const float* Wv = (const float*)d_in[3];
    float* out = (float*)d_out;
    char* ws = (char*)d_ws;

    u16* wt = (u16*)ws;                                    // [3][64][1024] bf16   (384 KB)
    u16* qk = (u16*)(ws + 3 * Hn * Cn * 2);                // 2 x [16384][64] bf16 (4 MB)
    u16* vt = qk + 2 * (size_t)Mrows * Hn;                 // [8][64][2048] bf16   (2 MB)
    float* partial = (float*)(ws + 3 * Hn * Cn * 2
                              + 2 * (size_t)Mrows * Hn * 2
                              + (size_t)Bn * Hn * Tn * 2); // 640 x 4224 f32       (10.8 MB)

    const float qscale = 0.04508422002778011f;  // C^-0.5 * log2(e)
    convert_w3<<<768, 256, 0, stream>>>(Wq, Wk, Wv, wt, qscale);
    qkv_proj<<<1024, 256, 0, stream>>>(x, wt, qk, vt);
    attn_fwd<<<Bn * UPB, 256, 0, stream>>>(qk, qk + (size_t)Mrows * Hn, vt, partial);
    attn_reduce<<<32 * Bn, 256, 0, stream>>>(partial, out);
}

// Round 10
// 62.497 us; speedup vs baseline: 1.4197x; 1.4197x over previous
//
#include <hip/hip_runtime.h>
#include <hip/hip_bf16.h>

typedef __attribute__((ext_vector_type(8))) short short8;
typedef __attribute__((ext_vector_type(4))) float f32x4;
typedef __attribute__((ext_vector_type(4))) unsigned short u16x4;
typedef unsigned short u16;

#define Bn 8
#define Tn 2048
#define Cn 1024
#define Hn 64
#define Mrows (Bn * Tn)  // 16384
#define UPB 320          // split-K work units per batch (16-row q-tiles)
#define SLOTF 1056       // floats per partial slot: 1024 o + 16 m + 16 l

__device__ __forceinline__ u16 bfu(float f) {
    __hip_bfloat16 h = __float2bfloat16(f);
    union { __hip_bfloat16 h; u16 u; } c; c.h = h; return c.u;
}

__device__ __forceinline__ short8 cvt8(f32x4 a0, f32x4 a1) {
    short8 r;
    r[0] = (short)bfu(a0[0]); r[1] = (short)bfu(a0[1]);
    r[2] = (short)bfu(a0[2]); r[3] = (short)bfu(a0[3]);
    r[4] = (short)bfu(a1[0]); r[5] = (short)bfu(a1[1]);
    r[6] = (short)bfu(a1[2]); r[7] = (short)bfu(a1[3]);
    return r;
}

// W [1024][64] f32 x3 -> wtf fragment-linear bf16: frag (ct 0..11, kcg 0..31),
// element (col = ct*16 + (lane&15), k = kcg*32 + (lane>>4)*8 + e) at
// wtf[(ct*32+kcg)*512 + lane*8 + e]. A wave's B-frag load = 1 KB contiguous.
__global__ void convert_w3(const float* __restrict__ Wq, const float* __restrict__ Wk,
                           const float* __restrict__ Wv, u16* __restrict__ wtf, float qscale) {
    int widx = blockIdx.x * 256 + threadIdx.x;          // 0 .. 196607
    int mat = widx >> 16;
    int rem = widx & 65535;
    int k = rem >> 6, n = rem & 63;
    const float* W = mat == 0 ? Wq : (mat == 1 ? Wk : Wv);
    float s = mat == 0 ? qscale : 1.0f;
    int ct = mat * 4 + (n >> 4);
    int lane = ((k >> 3) & 3) * 16 + (n & 15);
    wtf[(size_t)(ct * 32 + (k >> 5)) * 512 + lane * 8 + (k & 7)] = bfu(W[rem] * s);
}

// x [16384][1024] f32 @ W -> q/k/v in MFMA-fragment-linear layouts.
// BM=32, BK=128, 4 waves (wave wn owns 48 cols, both 16-row M-frags).
// B direct-coalesced from wtf (L2, no LDS); A reg-prefetched (issued AFTER the
// B loads so in-order vmcnt never stalls B on A's HBM latency) -> LDS
// (17x16B row stride = odd superbank stride, conflict-free b128).
__global__ __launch_bounds__(256) void qkv_proj(const float* __restrict__ x,
                                                const u16* __restrict__ wtf,
                                                u16* __restrict__ qfl,
                                                u16* __restrict__ kfl,
                                                u16* __restrict__ vfl) {
    __shared__ u16 As[32][136];
    const int tid = threadIdx.x;
    const int lane = tid & 63;
    const int wn = tid >> 6;          // 0..3 -> 48-col slice
    const int l15 = lane & 15;
    const int lhi = lane >> 4;
    const int row0 = blockIdx.x * 32;

    const int arow = tid >> 3;        // 0..31
    const int ac0 = (tid & 7) * 16;   // f32 col base 0..112
    const float* asrc = x + (size_t)(row0 + arow) * Cn + ac0;

    f32x4 acc[2][3];
    for (int mt = 0; mt < 2; ++mt)
        for (int nj = 0; nj < 3; ++nj) acc[mt][nj] = f32x4{0.f, 0.f, 0.f, 0.f};

    f32x4 ra0 = *(const f32x4*)(asrc);
    f32x4 ra1 = *(const f32x4*)(asrc + 4);
    f32x4 ra2 = *(const f32x4*)(asrc + 8);
    f32x4 ra3 = *(const f32x4*)(asrc + 12);

    for (int ks = 0; ks < 8; ++ks) {
        __syncthreads();
        *(short8*)&As[arow][ac0]     = cvt8(ra0, ra1);
        *(short8*)&As[arow][ac0 + 8] = cvt8(ra2, ra3);
        __syncthreads();
        #pragma unroll
        for (int kc = 0; kc < 4; ++kc) {
            short8 af0 = *(const short8*)&As[l15][kc * 32 + lhi * 8];
            short8 af1 = *(const short8*)&As[16 + l15][kc * 32 + lhi * 8];
            #pragma unroll
            for (int nj = 0; nj < 3; ++nj) {
                short8 bf = *(const short8*)(wtf + (size_t)((wn * 3 + nj) * 32 + ks * 4 + kc) * 512 + lane * 8);
                acc[0][nj] = __builtin_amdgcn_mfma_f32_16x16x32_bf16(af0, bf, acc[0][nj], 0, 0, 0);
                acc[1][nj] = __builtin_amdgcn_mfma_f32_16x16x32_bf16(af1, bf, acc[1][nj], 0, 0, 0);
            }
        }
        if (ks < 7) {
            const float* nsrc = asrc + (ks + 1) * 128;
            ra0 = *(const f32x4*)(nsrc);
            ra1 = *(const f32x4*)(nsrc + 4);
            ra2 = *(const f32x4*)(nsrc + 8);
            ra3 = *(const f32x4*)(nsrc + 12);
        }
    }

    // Epilogue: scatter acc into fragment-linear q/k/v.
    for (int mt = 0; mt < 2; ++mt) {
        const int growb = row0 + mt * 16 + lhi * 4;    // t = growb + r
        const int bI = growb >> 11;
        const int tloc = growb & 2047;
        for (int nj = 0; nj < 3; ++nj) {
            const int gcolb = wn * 48 + nj * 16;
            const int matid = gcolb >> 6;
            const int d0 = gcolb & 63;                 // multiple of 16
            if (matid < 2) {
                // q/k frag (g = t/16, kc = d0>>5): lane' = lhid*16 + (t%16), e' = d%8
                u16* dst = matid == 0 ? qfl : kfl;
                const int g = tloc >> 4;               // constant across r
                const int lhid = ((d0 & 31) + l15) >> 3;
                const size_t base = ((size_t)(bI * 128 + g) * 2 + (d0 >> 5)) * 512
                                    + (size_t)lhid * 128 + (l15 & 7);
                for (int r = 0; r < 4; ++r)
                    dst[base + (size_t)(lhi * 4 + r) * 8] = bfu(acc[mt][nj][r]);
            } else {
                // v frag (kt64 = t/64, dt = d0>>4, kc = (t%64)>>5):
                // lane' = ((t%32)>>3)*16 + (d%16), e' = t%8 (contiguous over r)
                const int kt64 = tloc >> 6;
                const int tin = tloc & 63;             // r=0 value; +r stays in chunk
                const int kcv = tin >> 5;
                const int lhiv = (tin & 31) >> 3;
                const int e0 = tin & 7;                // in {0,4}
                const int dt = d0 >> 4;
                u16x4 pk;
                pk[0] = bfu(acc[mt][nj][0]); pk[1] = bfu(acc[mt][nj][1]);
                pk[2] = bfu(acc[mt][nj][2]); pk[3] = bfu(acc[mt][nj][3]);
                *(u16x4*)(vfl + ((size_t)((bI * 32 + kt64) * 4 + dt) * 2 + kcv) * 512
                              + (size_t)(lhiv * 16 + l15) * 8 + e0) = pk;
            }
        }
    }
}

// Flash attention, causal, split-K (round-4 verified structure: 1 wave per
// (16 q-rows, <=512-key chunk), no barriers). All Q/K/V fragment loads are now
// single coalesced 1KB instructions from the fragment-linear layouts.
__global__ __launch_bounds__(64) void attn_fwd(const u16* __restrict__ qfl,
                                               const u16* __restrict__ kfl,
                                               const u16* __restrict__ vfl,
                                               float* __restrict__ partial) {
    __shared__ u16 pl[16][72];
    const int lane = threadIdx.x;
    const int l15 = lane & 15, lhi = lane >> 4;
    const int bid = blockIdx.x;
    const int b = bid / UPB;
    const int u = bid - b * UPB;
    int qt, c;
    if (u < 32)       { qt = u;                  c = 0; }
    else if (u < 96)  { qt = 32 + ((u - 32) >> 1);  c = (u - 32) & 1; }
    else if (u < 192) { qt = 64 + (u - 96) / 3;     c = (u - 96) % 3; }
    else              { qt = 96 + ((u - 192) >> 2); c = (u - 192) & 3; }
    const int nkt = (qt >> 2) + 1;
    const int kb0 = c * 8;
    const int kbe = min(kb0 + 8, nkt);
    const int q0 = qt * 16;

    const u16* qb = qfl + (size_t)b * 131072;
    const u16* kb = kfl + (size_t)b * 131072;
    const u16* vb = vfl + (size_t)b * 131072;

    short8 qf[2];
    for (int kc = 0; kc < 2; ++kc)
        qf[kc] = *(const short8*)(qb + ((size_t)(qt * 2 + kc) * 64 + lane) * 8);

    float m = -1e30f, lpart = 0.f;   // per-lane: q-row = l15 (4 copies across lhi)
    f32x4 o[4];
    for (int dt = 0; dt < 4; ++dt) o[dt] = f32x4{0.f, 0.f, 0.f, 0.f};

    for (int kbi = kb0; kbi < kbe; ++kbi) {
        const int k0 = kbi * 64;
        f32x4 sacc[4];
        for (int kt = 0; kt < 4; ++kt) sacc[kt] = f32x4{0.f, 0.f, 0.f, 0.f};
        // S^T = K·Q^T : D col = q (l15), D row = k-within-tile (lhi*4+r)
        #pragma unroll
        for (int kc = 0; kc < 2; ++kc) {
            #pragma unroll
            for (int kt = 0; kt < 4; ++kt) {
                short8 kf = *(const short8*)(kb + ((size_t)((kbi * 4 + kt) * 2 + kc) * 64 + lane) * 8);
                sacc[kt] = __builtin_amdgcn_mfma_f32_16x16x32_bf16(kf, qf[kc], sacc[kt], 0, 0, 0);
            }
        }
        if (kbi == nkt - 1) {  // diagonal tile: causal mask (per-lane, no shuffle)
            for (int kt = 0; kt < 4; ++kt)
                for (int r = 0; r < 4; ++r) {
                    int kg = k0 + kt * 16 + lhi * 4 + r;
                    if (kg > q0 + l15) sacc[kt][r] = -3.0e38f;
                }
        }
        f32x4 mx0, mx1;
        for (int e = 0; e < 4; ++e) {
            mx0[e] = fmaxf(sacc[0][e], sacc[1][e]);
            mx1[e] = fmaxf(sacc[2][e], sacc[3][e]);
        }
        float tmax = -3.0e38f;
        for (int e = 0; e < 4; ++e) tmax = fmaxf(tmax, fmaxf(mx0[e], mx1[e]));
        tmax = fmaxf(tmax, __shfl_xor(tmax, 16));
        tmax = fmaxf(tmax, __shfl_xor(tmax, 32));
        if (!__all(tmax <= m + 8.0f)) {   // defer-max (THR=8, log2 domain)
            float mnew = fmaxf(m, tmax);
            float corr = exp2f(m - mnew);
            m = mnew;
            lpart *= corr;
            for (int r = 0; r < 4; ++r) {
                float cr = __shfl(corr, lhi * 4 + r);
                for (int dt = 0; dt < 4; ++dt) o[dt][r] *= cr;
            }
        }
        float psum = 0.f;
        for (int kt = 0; kt < 4; ++kt)
            for (int r = 0; r < 4; ++r) {
                float p = exp2f(sacc[kt][r] - m);
                sacc[kt][r] = p;
                psum += p;
            }
        lpart += psum;
        // P -> LDS (wave-private transpose to A-frag layout)
        for (int kt = 0; kt < 4; ++kt) {
            u16x4 pk;
            pk[0] = bfu(sacc[kt][0]); pk[1] = bfu(sacc[kt][1]);
            pk[2] = bfu(sacc[kt][2]); pk[3] = bfu(sacc[kt][3]);
            *(u16x4*)&pl[l15][kt * 16 + lhi * 4] = pk;
        }
        short8 pf[2];
        for (int kc = 0; kc < 2; ++kc)
            pf[kc] = *(const short8*)&pl[l15][kc * 32 + lhi * 8];
        // O += P·V : V-frags coalesced from vfl
        #pragma unroll
        for (int dt = 0; dt < 4; ++dt) {
            #pragma unroll
            for (int kc = 0; kc < 2; ++kc) {
                short8 vf = *(const short8*)(vb + ((size_t)((kbi * 4 + dt) * 2 + kc) * 512 + lane * 8));
                o[dt] = __builtin_amdgcn_mfma_f32_16x16x32_bf16(pf[kc], vf, o[dt], 0, 0, 0);
            }
        }
    }
    float lsum = lpart;
    lsum += __shfl_xor(lsum, 16);
    lsum += __shfl_xor(lsum, 32);

    float* ps = partial + (size_t)bid * SLOTF;
    for (int dt = 0; dt < 4; ++dt)
        for (int r = 0; r < 4; ++r)
            ps[(lhi * 4 + r) * 64 + dt * 16 + l15] = o[dt][r];
    if (lhi == 0) {
        ps[1024 + l15] = m;
        ps[1040 + l15] = lsum;
    }
}

// Combine <=4 split-K partials per (b, 16-row q-tile). (Round-4 verified.)
__global__ __launch_bounds__(256) void attn_reduce(const float* __restrict__ partial,
                                                   float* __restrict__ out) {
    const int bid = blockIdx.x;           // 0..1023
    const int b = bid >> 7, qt = bid & 127;
    const int nc = qt < 32 ? 1 : qt < 64 ? 2 : qt < 96 ? 3 : 4;
    const int base = b * UPB +
        (qt < 32 ? qt : qt < 64 ? 32 + 2 * (qt - 32)
                      : qt < 96 ? 96 + 3 * (qt - 64) : 192 + 4 * (qt - 96));
    const int d = threadIdx.x & 63;
    const int qr = threadIdx.x >> 6;
    for (int i = 0; i < 4; ++i) {
        const int qq = i * 4 + qr;
        float M = -3.0e38f;
        #pragma unroll
        for (int cc = 0; cc < 4; ++cc)
            if (cc < nc) M = fmaxf(M, partial[(size_t)(base + cc) * SLOTF + 1024 + qq]);
        float L = 0.f, acc = 0.f;
        #pragma unroll
        for (int cc = 0; cc < 4; ++cc)
            if (cc < nc) {
                const float* ps = partial + (size_t)(base + cc) * SLOTF;
                float w = exp2f(ps[1024 + qq] - M);
                L += ps[1040 + qq] * w;
                acc += ps[qq * 64 + d] * w;
            }
        out[((size_t)b * Tn + qt * 16 + qq) * Hn + d] = acc / L;
    }
}

extern "C" void kernel_launch(void* const* d_in, const int* in_sizes, int n_in,
                              void* d_out, int out_size, void* d_ws, size_t ws_size,
                              hipStream_t stream) {
    const float* x = (const float*)d_in[0];
    const float* Wq = (const float*)d_in[1];
    const float* Wk = (const float*)d_in[2];
    const float* Wv = (const float*)d_in[3];
    float* out = (float*)d_out;
    char* ws = (char*)d_ws;

    u16* wtf = (u16*)ws;                                   // 12*32*512 u16 (384 KB)
    u16* qfl = (u16*)(ws + 196608 * 2);                    // 8*131072 u16 (2 MB)
    u16* kfl = qfl + (size_t)Bn * 131072;                  // 2 MB
    u16* vfl = kfl + (size_t)Bn * 131072;                  // 2 MB
    float* partial = (float*)(ws + 196608 * 2 + 3 * (size_t)Bn * 131072 * 2); // 10.8 MB

    const float qscale = 0.04508422002778011f;  // C^-0.5 * log2(e)
    convert_w3<<<768, 256, 0, stream>>>(Wq, Wk, Wv, wtf, qscale);
    qkv_proj<<<Mrows / 32, 256, 0, stream>>>(x, wtf, qfl, kfl, vfl);
    attn_fwd<<<Bn * UPB, 64, 0, stream>>>(qfl, kfl, vfl, partial);
    attn_reduce<<<128 * Bn, 256, 0, stream>>>(partial, out);
}